// Round 6
// baseline (1584.172 us; speedup 1.0000x reference)
//
#include <hip/hip_runtime.h>
#include <math.h>

#define HH 96
#define WWI 96
#define NN 9216        // H*W
#define CC 256
#define LL 9216
#define CHK 96
#define NCH 96
#define BB 8
#define BN (BB*NN)     // 73728

__device__ __forceinline__ float softplusf(float x){
    float e = expf(-fabsf(x));
    return fmaxf(x, 0.f) + log1pf(e);
}
__device__ __forceinline__ float sigmf(float x){ return 1.f / (1.f + expf(-x)); }

__device__ __forceinline__ float wredsum(float v){
    #pragma unroll
    for(int o = 32; o > 0; o >>= 1) v += __shfl_xor(v, o, 64);
    return v;
}

// scan chunk -> spatial walk: n = base + j*step, j = 0..95 (within-chunk scan order)
__device__ __forceinline__ void chunk_walk(int g, int chunk, int& base, int& step){
    if(g == 0){ base = chunk * 96;        step = 1;   }
    else if(g == 1){ base = 9215 - chunk * 96; step = -1; }
    else if(g == 2){ base = chunk;        step = 96;  }
    else { base = 9215 - chunk;           step = -96; }
}

// ---------------- K1: per-row LN stats of x -> mrs (mean, rstd) ------------------
__global__ __launch_bounds__(256) void k_stats(const float* __restrict__ x,
                                               float* __restrict__ mrs){
    int wid = threadIdx.x >> 6, lane = threadIdx.x & 63;
    size_t row = (size_t)blockIdx.x * 4 + wid;
    float4 v = ((const float4*)(x + row * CC))[lane];
    float s = wredsum(v.x + v.y + v.z + v.w);
    float q = wredsum(v.x*v.x + v.y*v.y + v.z*v.z + v.w*v.w);
    float m = s * (1.f/256.f);
    float var = q * (1.f/256.f) - m*m;
    float rs = rsqrtf(fmaxf(var, 0.f) + 1e-5f);
    if(lane == 0){ mrs[2*row] = m; mrs[2*row+1] = rs; }
}

// ---------------- K2: partial column sums of LN(x) -> zpart ----------------------
__global__ __launch_bounds__(256) void k_zavg(const float* __restrict__ x,
        const float* __restrict__ mrs, const float* __restrict__ nw,
        const float* __restrict__ nb, float* __restrict__ zpart){
    int c = threadIdx.x, b = blockIdx.y, t0 = blockIdx.x * 256;
    float nwv = nw[c], nbv = nb[c];
    float s = 0.f;
    for(int i = 0; i < 256; i++){
        size_t r = (size_t)b * NN + t0 + i;
        s += (x[r * CC + c] - mrs[2*r]) * mrs[2*r+1] * nwv + nbv;
    }
    zpart[((size_t)b * 36 + blockIdx.x) * CC + c] = s;
}

// ---------------- K3: gate = sigmoid(z@fc_w.T + fc_b + conv1d(z)) ----------------
__global__ __launch_bounds__(256) void k_gate(const float* __restrict__ zpart,
        const float* __restrict__ fcw, const float* __restrict__ fcb,
        const float* __restrict__ w1d, float* __restrict__ gate){
    __shared__ float za[CC];
    int c = threadIdx.x, b = blockIdx.x;
    float s = 0.f;
    for(int t = 0; t < 36; t++) s += zpart[((size_t)b * 36 + t) * CC + c];
    za[c] = s * (1.f/(float)NN);
    __syncthreads();
    float zm1 = (c > 0)     ? za[c-1] : 0.f;
    float zp1 = (c < CC-1)  ? za[c+1] : 0.f;
    float acc = fcb[c] + w1d[0]*zm1 + w1d[1]*za[c] + w1d[2]*zp1;
    const float* wr = fcw + (size_t)c * CC;
    for(int k = 0; k < CC; k++) acc += za[k] * wr[k];
    gate[b * CC + c] = sigmf(acc);
}

// ------ K4: fused LN + in_proj(x half) + depthwise conv3x3 + silu ----------------
// 8x8 tile, 10x10 halo. Writes s = silu(conv) in SPATIAL layout into d_out.
__global__ __launch_bounds__(256) void k_ipconv(const float* __restrict__ x,
        const float* __restrict__ mrs, const float* __restrict__ nw,
        const float* __restrict__ nb, const float* __restrict__ ipw,
        const float* __restrict__ ipb, const float* __restrict__ cw,
        const float* __restrict__ cb, float* __restrict__ out){
    int tile = blockIdx.x, b = blockIdx.y, g = blockIdx.z;
    int h0 = (tile / 12) * 8, w0 = (tile % 12) * 8;
    __shared__ float xs[100 * 64];
    __shared__ float xi[100 * 64];
    int tid = threadIdx.x;
    for(int i = tid; i < 6400; i += 256){
        int p = i >> 6, k = i & 63;
        int ph = h0 + p / 10 - 1, pw = w0 + p % 10 - 1;
        float v = 0.f;
        if(ph >= 0 && ph < HH && pw >= 0 && pw < WWI){
            size_t r = (size_t)b * NN + ph * WWI + pw;
            v = (x[r * CC + g*64 + k] - mrs[2*r]) * mrs[2*r+1]
                * nw[g*64 + k] + nb[g*64 + k];
        }
        xs[i] = v;
    }
    __syncthreads();
    int c = tid & 63, q = tid >> 6;
    {
        float wv[64];
        const float* wr = ipw + ((size_t)(g * 128 + c)) * 64;
        #pragma unroll
        for(int k = 0; k < 64; k++) wv[k] = wr[k];
        float bias = ipb[g * 128 + c];
        for(int p = q * 25; p < q * 25 + 25; p++){
            int ph = h0 + p / 10 - 1, pw = w0 + p % 10 - 1;
            bool valid = (ph >= 0 && ph < HH && pw >= 0 && pw < WWI);
            float acc = bias;
            const float* xp = &xs[p * 64];
            #pragma unroll
            for(int k = 0; k < 64; k++) acc += xp[k] * wv[k];
            xi[p * 64 + c] = valid ? acc : 0.f;   // conv zero-pads AFTER in_proj
        }
    }
    __syncthreads();
    float wk[9];
    const float* wp = cw + ((size_t)(g * 64 + c)) * 9;
    #pragma unroll
    for(int j = 0; j < 9; j++) wk[j] = wp[j];
    float bias2 = cb[g * 64 + c];
    for(int pi = q * 16; pi < q * 16 + 16; pi++){
        int py = pi >> 3, px = pi & 7;
        float acc = bias2;
        #pragma unroll
        for(int dy = 0; dy < 3; dy++)
            #pragma unroll
            for(int dx = 0; dx < 3; dx++)
                acc += xi[((py + dy) * 10 + px + dx) * 64 + c] * wk[dy*3 + dx];
        float sv = acc * sigmf(acc);
        size_t r = (size_t)b * NN + (h0 + py) * WWI + (w0 + px);
        out[r * CC + g*64 + c] = sv;
    }
}

// ---------------- K5: scan phase 1 — on-the-fly xdbl, prod(a), h_end -------------
__global__ __launch_bounds__(64) void k_scan1(const float* __restrict__ out,
        const float* __restrict__ xpw, const float* __restrict__ dtw,
        const float* __restrict__ dtb, const float* __restrict__ alog,
        float* __restrict__ ap_out, float* __restrict__ h_out){
    int chunk = blockIdx.x, gb = blockIdx.y;
    int g = gb >> 3, b = gb & 7, d = threadIdx.x;
    __shared__ float s_seq[CHK * 65];
    __shared__ float s_xd[CHK * 6];
    __shared__ float s_w[6 * 64];
    int base, step; chunk_walk(g, chunk, base, step);
    const float* xg = out + (size_t)b * NN * CC + g * 64;
    for(int j = 0; j < CHK; j++)
        s_seq[j * 65 + d] = xg[(size_t)(base + j * step) * CC + d];
    for(int i = d; i < 384; i += 64) s_w[i] = xpw[g * 384 + i];
    __syncthreads();
    for(int idx = d; idx < CHK*6; idx += 64){
        int l = idx / 6, j = idx % 6;
        float acc = 0.f;
        const float* sr = &s_seq[l * 65];
        const float* wr = &s_w[j * 64];
        #pragma unroll
        for(int k = 0; k < 64; k++) acc += sr[k] * wr[k];
        s_xd[idx] = acc;
    }
    __syncthreads();
    int gd = g * 64 + d;
    float Av = -expf(alog[gd]);
    float db = dtb[gd];
    float w0 = dtw[gd*4], w1 = dtw[gd*4+1], w2 = dtw[gd*4+2], w3 = dtw[gd*4+3];
    float h = 0.f, apd = 1.f;
    for(int l = 0; l < CHK; l++){
        const float* xd = &s_xd[l * 6];
        float xv = s_seq[l*65 + d];
        float dt = softplusf(xd[0]*w0 + xd[1]*w1 + xd[2]*w2 + xd[3]*w3 + db);
        float a = expf(dt * Av);
        h = a*h + dt*xv*xd[4];
        apd *= a;
    }
    int ob = (gb * NCH + chunk) * 64 + d;
    ap_out[ob] = apd; h_out[ob] = h;
}

// ---------------- K6: scan phase 2 — serial scan over chunk summaries ------------
__global__ __launch_bounds__(256) void k_scan2(const float* __restrict__ ap,
        const float* __restrict__ he, float* __restrict__ hinit){
    int idx = blockIdx.x * 256 + threadIdx.x;   // 0..2047
    int gb = idx >> 6, d = idx & 63;
    float h = 0.f;
    for(int c = 0; c < NCH; c++){
        int o = (gb * NCH + c) * 64 + d;
        hinit[o] = h;
        h = ap[o]*h + he[o];
    }
}

// --- K7: scan phase 3 + out_norm LN + z-recompute + silu gate, IN PLACE ----------
__global__ __launch_bounds__(64) void k_scan3(float* __restrict__ out,
        const float* __restrict__ x, const float* __restrict__ mrs,
        const float* __restrict__ nw, const float* __restrict__ nb,
        const float* __restrict__ ipw, const float* __restrict__ ipb,
        const float* __restrict__ xpw, const float* __restrict__ dtw,
        const float* __restrict__ dtb, const float* __restrict__ alog,
        const float* __restrict__ Dsp, const float* __restrict__ onw,
        const float* __restrict__ onb, const float* __restrict__ hinit){
    int chunk = blockIdx.x, gb = blockIdx.y;
    int g = gb >> 3, b = gb & 7, d = threadIdx.x;
    __shared__ float s_seq[CHK * 65];
    __shared__ float xnt[CHK * 65];
    __shared__ float s_xd[CHK * 6];
    __shared__ float s_w[6 * 64];
    int base, step; chunk_walk(g, chunk, base, step);
    float* xg = out + (size_t)b * NN * CC + g * 64;
    float nwv = nw[g*64 + d], nbv = nb[g*64 + d];
    for(int j = 0; j < CHK; j++){
        int n = base + j * step;
        s_seq[j * 65 + d] = xg[(size_t)n * CC + d];
        size_t r = (size_t)b * NN + n;
        xnt[j * 65 + d] = (x[r * CC + g*64 + d] - mrs[2*r]) * mrs[2*r+1] * nwv + nbv;
    }
    for(int i = d; i < 384; i += 64) s_w[i] = xpw[g * 384 + i];
    __syncthreads();
    for(int idx = d; idx < CHK*6; idx += 64){
        int l = idx / 6, j = idx % 6;
        float acc = 0.f;
        const float* sr = &s_seq[l * 65];
        const float* wr = &s_w[j * 64];
        #pragma unroll
        for(int k = 0; k < 64; k++) acc += sr[k] * wr[k];
        s_xd[idx] = acc;
    }
    __syncthreads();
    int gd = g * 64 + d;
    float Av = -expf(alog[gd]);
    float db = dtb[gd];
    float Dv = Dsp[gd];
    float wON = onw[gd], bON = onb[gd];
    float w0 = dtw[gd*4], w1 = dtw[gd*4+1], w2 = dtw[gd*4+2], w3 = dtw[gd*4+3];
    float wz[64];   // z-half in_proj row for output channel d
    {
        const float* wr = ipw + ((size_t)(g * 128 + 64 + d)) * 64;
        #pragma unroll
        for(int k = 0; k < 64; k++) wz[k] = wr[k];
    }
    float zb = ipb[g * 128 + 64 + d];
    float h = hinit[(gb * NCH + chunk) * 64 + d];
    for(int l = 0; l < CHK; l++){
        const float* xd = &s_xd[l * 6];
        float xv = s_seq[l*65 + d];
        float dt = softplusf(xd[0]*w0 + xd[1]*w1 + xd[2]*w2 + xd[3]*w3 + db);
        float a = expf(dt * Av);
        h = a*h + dt*xv*xd[4];
        float y = h * xd[5] + Dv * xv;
        float s = wredsum(y);
        float q = wredsum(y * y);
        float m = s * (1.f/64.f);
        float var = q * (1.f/64.f) - m*m;
        float rs = rsqrtf(fmaxf(var, 0.f) + 1e-5f);
        float lny = (y - m) * rs * wON + bON;
        float z = zb;
        const float* xp = &xnt[l * 65];
        #pragma unroll
        for(int k = 0; k < 64; k++) z += xp[k] * wz[k];
        float y2 = lny * (z * sigmf(z));
        xg[(size_t)(base + l * step) * CC + d] = y2;   // in-place (own tile)
    }
}

// --- K8: out_proj + skip*xn*gate, spatial tiles, IN PLACE ------------------------
__global__ __launch_bounds__(64) void k_out2(float* __restrict__ out,
        const float* __restrict__ x, const float* __restrict__ mrs,
        const float* __restrict__ nw, const float* __restrict__ nb,
        const float* __restrict__ opw, const float* __restrict__ opb,
        const float* __restrict__ gate, const float* __restrict__ skip){
    int tile = blockIdx.x, b = blockIdx.y, g = blockIdx.z;
    int n0 = tile * 64, t = threadIdx.x;
    __shared__ float ly[64 * 65];
    __shared__ float xnt[64 * 65];
    float* xg = out + (size_t)b * NN * CC + g * 64;
    float nwv = nw[g*64 + t], nbv = nb[g*64 + t];
    for(int p = 0; p < 64; p++){
        size_t r = (size_t)b * NN + n0 + p;
        ly[p * 65 + t] = xg[(size_t)(n0 + p) * CC + t];
        xnt[p * 65 + t] = (x[r * CC + g*64 + t] - mrs[2*r]) * mrs[2*r+1] * nwv + nbv;
    }
    __syncthreads();
    float wv[64];
    const float* wr = opw + ((size_t)(g * 64 + t)) * 64;
    #pragma unroll
    for(int k = 0; k < 64; k++) wv[k] = wr[k];
    float bias = opb[g * 64 + t];
    float gv = gate[b * CC + g*64 + t];
    float sk = skip[0];
    for(int p = 0; p < 64; p++){
        float acc = bias;
        const float* yp = &ly[p * 65];
        #pragma unroll
        for(int k = 0; k < 64; k++) acc += yp[k] * wv[k];
        xg[(size_t)(n0 + p) * CC + t] = acc * sk * xnt[p * 65 + t] * gv;
    }
}

// ---------------- K9: final LN + proj GEMM, IN PLACE (reads rows, writes rows) ---
__global__ __launch_bounds__(256) void k_final(float* __restrict__ out,
        const float* __restrict__ nw, const float* __restrict__ nb,
        const float* __restrict__ pw, const float* __restrict__ pb){
    __shared__ float A[16 * 256];
    __shared__ float ps[256], pq[256];
    __shared__ float mrow[16], rrow[16];
    int n0 = blockIdx.x * 16;
    for(int i = threadIdx.x; i < 4096; i += 256)
        A[i] = out[(size_t)n0 * CC + i];
    __syncthreads();
    {
        int r = threadIdx.x >> 4, t16 = threadIdx.x & 15;
        float s = 0.f, q = 0.f;
        for(int j = 0; j < 16; j++){
            float v = A[r*256 + t16*16 + j];
            s += v; q += v*v;
        }
        ps[threadIdx.x] = s; pq[threadIdx.x] = q;
    }
    __syncthreads();
    if(threadIdx.x < 16){
        float ss = 0.f, qq = 0.f;
        for(int j = 0; j < 16; j++){ ss += ps[threadIdx.x*16 + j]; qq += pq[threadIdx.x*16 + j]; }
        float m = ss * (1.f/256.f);
        float var = qq * (1.f/256.f) - m*m;
        mrow[threadIdx.x] = m;
        rrow[threadIdx.x] = rsqrtf(fmaxf(var, 0.f) + 1e-5f);
    }
    __syncthreads();
    for(int i = threadIdx.x; i < 4096; i += 256){
        int r = i >> 8, c = i & 255;
        A[i] = (A[i] - mrow[r]) * rrow[r] * nw[c] + nb[c];
    }
    __syncthreads();
    int o = threadIdx.x;
    float acc[16];
    #pragma unroll
    for(int p = 0; p < 16; p++) acc[p] = 0.f;
    for(int kt = 0; kt < 4; kt++){
        float wv[64];
        const float4* wr = (const float4*)(pw + (size_t)o * CC + kt * 64);
        #pragma unroll
        for(int j = 0; j < 16; j++){
            float4 tq = wr[j];
            wv[4*j+0] = tq.x; wv[4*j+1] = tq.y;
            wv[4*j+2] = tq.z; wv[4*j+3] = tq.w;
        }
        #pragma unroll
        for(int p = 0; p < 16; p++){
            const float* ar = &A[p*256 + kt*64];
            float a = 0.f;
            #pragma unroll
            for(int k = 0; k < 64; k++) a += ar[k] * wv[k];
            acc[p] += a;
        }
    }
    float pbv = pb[o];
    #pragma unroll
    for(int p = 0; p < 16; p++)
        out[(size_t)(n0 + p) * CC + o] = acc[p] + pbv;
}

extern "C" void kernel_launch(void* const* d_in, const int* in_sizes, int n_in,
                              void* d_out, int out_size, void* d_ws, size_t ws_size,
                              hipStream_t stream){
    const float* x    = (const float*)d_in[0];
    const float* nw   = (const float*)d_in[1];
    const float* nb   = (const float*)d_in[2];
    const float* fcw  = (const float*)d_in[3];
    const float* fcb  = (const float*)d_in[4];
    const float* w1d  = (const float*)d_in[5];
    const float* ipw  = (const float*)d_in[6];
    const float* ipb  = (const float*)d_in[7];
    const float* cw   = (const float*)d_in[8];
    const float* cb   = (const float*)d_in[9];
    const float* xpw  = (const float*)d_in[10];
    const float* dtw  = (const float*)d_in[11];
    const float* dtb  = (const float*)d_in[12];
    const float* alog = (const float*)d_in[13];
    const float* Dsp  = (const float*)d_in[14];
    const float* onw  = (const float*)d_in[15];
    const float* onb  = (const float*)d_in[16];
    const float* opw  = (const float*)d_in[17];
    const float* opb  = (const float*)d_in[18];
    const float* pw   = (const float*)d_in[19];
    const float* pb   = (const float*)d_in[20];
    const float* skip = (const float*)d_in[21];

    // Workspace: TOTAL 2,957,312 B (~2.82 MB)
    char* base = (char*)d_ws;
    float* mrs  = (float*)base;                     //   589,824 B
    float* gate = (float*)(base +  589824ull);      //     8,192 B
    float* ap   = (float*)(base +  598016ull);      //   786,432 B (zpart aliases)
    float* he   = (float*)(base + 1384448ull);      //   786,432 B
    float* hi   = (float*)(base + 2170880ull);      //   786,432 B
    float* zpart = ap;                              // dead before k_scan1 writes ap
    float* out  = (float*)d_out;                    // spatial (B,N,256) at all stages
    (void)in_sizes; (void)n_in; (void)out_size; (void)ws_size;

    k_stats <<<18432, 256, 0, stream>>>(x, mrs);
    k_zavg  <<<dim3(36, 8), 256, 0, stream>>>(x, mrs, nw, nb, zpart);
    k_gate  <<<8, 256, 0, stream>>>(zpart, fcw, fcb, w1d, gate);
    k_ipconv<<<dim3(144, 8, 4), 256, 0, stream>>>(x, mrs, nw, nb, ipw, ipb, cw, cb, out);
    k_scan1 <<<dim3(96, 32), 64, 0, stream>>>(out, xpw, dtw, dtb, alog, ap, he);
    k_scan2 <<<8, 256, 0, stream>>>(ap, he, hi);
    k_scan3 <<<dim3(96, 32), 64, 0, stream>>>(out, x, mrs, nw, nb, ipw, ipb, xpw,
                                              dtw, dtb, alog, Dsp, onw, onb, hi);
    k_out2  <<<dim3(144, 8, 4), 64, 0, stream>>>(out, x, mrs, nw, nb, opw, opb,
                                                 gate, skip);
    k_final <<<4608, 256, 0, stream>>>(out, nw, nb, pw, pb);
}